// Round 7
// baseline (65.178 us; speedup 1.0000x reference)
//
#include <hip/hip_runtime.h>
#include <hip/hip_fp16.h>
#include <math.h>

#define NQ 8
#define DK 64
#define NB 8
#define NS 1024
#define RB 8            // rows per block in attn kernel

__device__ __forceinline__ float rfl(float x) {
    return __int_as_float(__builtin_amdgcn_readfirstlane(__float_as_int(x)));
}

// ---------------- prep: values GEMM (blocks 0..2047) + density features (2048..2303) ----------------
// qd fp32 [tok][n*4 + {d0,d1,re,im}]; kd fp16 same layout with factor 2 on cross terms.
__global__ __launch_bounds__(256) void prep_kernel(
    const float* __restrict__ x,
    const float* __restrict__ theta_q,
    const float* __restrict__ theta_k,
    const float* __restrict__ Wv,
    const float* __restrict__ bv,
    float* __restrict__ qd, __half* __restrict__ kdh,
    float* __restrict__ values) {
    int bid = blockIdx.x;
    int tid = threadIdx.x;
    if (bid < 2048) {
        // values = x @ Wv^T + bv (4 partial chains to break FMA dependency)
        int t = bid * 4 + (tid >> 6);
        int d = tid & 63;
        const float4* xr = (const float4*)(x + (size_t)t * DK);
        const float4* wr = (const float4*)(Wv + (size_t)d * DK);
        float a0 = bv[d], a1 = 0.f, a2 = 0.f, a3 = 0.f;
#pragma unroll
        for (int j = 0; j < DK / 4; ++j) {
            float4 xv = xr[j], wv = wr[j];
            a0 = fmaf(xv.x, wv.x, a0);
            a1 = fmaf(xv.y, wv.y, a1);
            a2 = fmaf(xv.z, wv.z, a2);
            a3 = fmaf(xv.w, wv.w, a3);
        }
        values[(size_t)t * DK + d] = (a0 + a1) + (a2 + a3);
    } else {
        int gid = (bid - 2048) * 256 + tid;   // 0..65535
        int tok = gid >> 3;
        int n = gid & 7;
        float xin = x[(size_t)tok * DK + n];
        float ex = __expf(2.0f * xin);               // fast tanh
        float xn = 1.0f - 2.0f / (ex + 1.0f);
        float half = xn * 1.57079632679489662f;      // xn * pi/2
        float s, c;
        __sincosf(half, &s, &c);

        // Q side (fp32)
        {
            float phi = theta_q[n * 3 + 0], th = theta_q[n * 3 + 1], om = theta_q[n * 3 + 2];
            float st, ct; __sincosf(0.5f * th, &st, &ct);
            float smpo, cmpo; __sincosf(0.5f * (phi + om), &smpo, &cmpo);
            float spmo, cpmo; __sincosf(0.5f * (phi - om), &spmo, &cpmo);
            float a = ct * c, b = st * s, cc = st * c, d = ct * s;
            float a0re =  cmpo * a - cpmo * b;
            float a0im = -smpo * a - spmo * b;
            float a1re =  cpmo * cc + cmpo * d;
            float a1im = -spmo * cc + smpo * d;
            float d0 = fmaf(a0re, a0re, a0im * a0im);
            float d1 = fmaf(a1re, a1re, a1im * a1im);
            float ur = fmaf(a1re, a0re, a1im * a0im);
            float ui = fmaf(a1im, a0re, -a1re * a0im);
            *(float4*)&qd[(size_t)tok * 32 + n * 4] = make_float4(d0, d1, ur, ui);
        }
        // K side (fp16, factor 2 on cross terms)
        {
            float phi = theta_k[n * 3 + 0], th = theta_k[n * 3 + 1], om = theta_k[n * 3 + 2];
            float st, ct; __sincosf(0.5f * th, &st, &ct);
            float smpo, cmpo; __sincosf(0.5f * (phi + om), &smpo, &cmpo);
            float spmo, cpmo; __sincosf(0.5f * (phi - om), &spmo, &cpmo);
            float a = ct * c, b = st * s, cc = st * c, d = ct * s;
            float a0re =  cmpo * a - cpmo * b;
            float a0im = -smpo * a - spmo * b;
            float a1re =  cpmo * cc + cmpo * d;
            float a1im = -spmo * cc + smpo * d;
            float d0 = fmaf(a0re, a0re, a0im * a0im);
            float d1 = fmaf(a1re, a1re, a1im * a1im);
            float ur = fmaf(a1re, a0re, a1im * a0im);
            float ui = fmaf(a1im, a0re, -a1re * a0im);
            __half2* kp = (__half2*)(kdh + (size_t)tok * 32 + n * 4);
            kp[0] = __floats2half2_rn(d0, d1);
            kp[1] = __floats2half2_rn(2.f * ur, 2.f * ui);
        }
    }
}

// ---------------- attn: fused scores -> softmax -> attn + PV ----------------
// 1024 blocks x 256 threads; block = 8 rows; wave w owns rows 2w,2w+1 (q in SGPRs).
__global__ __launch_bounds__(256, 4) void attn_kernel(
    const float* __restrict__ qd, const __half* __restrict__ kdh,
    const float* __restrict__ values,
    float* __restrict__ out, float* __restrict__ attn) {
    __shared__ __align__(16) __half e16[RB][NS];   // 16 KB, reused as fp32 reduce scratch
    __shared__ float inv_lds[RB];

    int tid = threadIdx.x;
    int gr0 = blockIdx.x * RB;            // global row base (= b*NS + s0)
    int b = gr0 >> 10;
    int w = tid >> 6, lane = tid & 63;

    // wave-uniform Q density features for rows 2w, 2w+1 -> SGPRs via readfirstlane
    float qa[32], qb[32];
    {
        const float4* qp0 = (const float4*)(qd + ((size_t)(gr0 + 2 * w)) * 32);
        const float4* qp1 = (const float4*)(qd + ((size_t)(gr0 + 2 * w + 1)) * 32);
#pragma unroll
        for (int cč = 0; cč < 8; ++cč) {
            float4 v0 = qp0[cč], v1 = qp1[cč];
            qa[cč * 4 + 0] = rfl(v0.x); qa[cč * 4 + 1] = rfl(v0.y);
            qa[cč * 4 + 2] = rfl(v0.z); qa[cč * 4 + 3] = rfl(v0.w);
            qb[cč * 4 + 0] = rfl(v1.x); qb[cč * 4 + 1] = rfl(v1.y);
            qb[cč * 4 + 2] = rfl(v1.z); qb[cč * 4 + 3] = rfl(v1.w);
        }
    }

    const __half* kfb = kdh + (size_t)b * NS * 32;

    // ---- Phase 1: scores + exp; wave covers all 1024 tokens for its 2 rows ----
    float sum0 = 0.f, sum1 = 0.f;
    for (int it = 0; it < 16; ++it) {
        int t = it * 64 + lane;
        const float4* kp = (const float4*)(kfb + ((size_t)t) * 32);  // 64 B = 4 x float4
        float kf[32];
#pragma unroll
        for (int cc = 0; cc < 4; ++cc) {
            float4 raw = kp[cc];
            __half2* hp = (__half2*)&raw;
#pragma unroll
            for (int j = 0; j < 4; ++j) {
                float2 f = __half22float2(hp[j]);
                kf[cc * 8 + j * 2 + 0] = f.x;
                kf[cc * 8 + j * 2 + 1] = f.y;
            }
        }
        float core0 = 1.f, core1 = 1.f;
#pragma unroll
        for (int n = 0; n < 8; ++n) {
            float k0 = kf[n*4+0], k1 = kf[n*4+1], k2 = kf[n*4+2], k3 = kf[n*4+3];
            core0 *= fmaf(qa[n*4+0], k0, fmaf(qa[n*4+1], k1, fmaf(qa[n*4+2], k2, qa[n*4+3] * k3)));
            core1 *= fmaf(qb[n*4+0], k0, fmaf(qb[n*4+1], k1, fmaf(qb[n*4+2], k2, qb[n*4+3] * k3)));
        }
        float e0 = __expf(fmaf(core0, 0.5f, 0.5f));  // score in [0.5,1] -> no max needed
        float e1 = __expf(fmaf(core1, 0.5f, 0.5f));
        e16[2 * w + 0][t] = __float2half_rn(e0);
        e16[2 * w + 1][t] = __float2half_rn(e1);
        sum0 += e0;
        sum1 += e1;
    }
#pragma unroll
    for (int msk = 1; msk < 64; msk <<= 1) {
        sum0 += __shfl_xor(sum0, msk, 64);
        sum1 += __shfl_xor(sum1, msk, 64);
    }
    if (lane == 0) {
        inv_lds[2 * w + 0] = 1.f / sum0;
        inv_lds[2 * w + 1] = 1.f / sum1;
    }
    __syncthreads();

    // ---- Phase 2: write normalized attn (coalesced float4) ----
    float* ab = attn + (size_t)gr0 * NS;
#pragma unroll
    for (int r = 0; r < RB; ++r) {
        float2 raw = *(const float2*)&e16[r][tid * 4];
        __half2* hp = (__half2*)&raw;
        float2 lo = __half22float2(hp[0]), hi = __half22float2(hp[1]);
        float iv = inv_lds[r];
        *(float4*)&ab[(size_t)r * NS + tid * 4] =
            make_float4(lo.x * iv, lo.y * iv, hi.x * iv, hi.y * iv);
    }

    // ---- Phase 3: PV on unnormalized e; thread (tg,dg) ----
    int tg = tid >> 4, dg = tid & 15;
    const float* vb = values + (size_t)b * NS * DK;
    float acc[RB][4];
#pragma unroll
    for (int r = 0; r < RB; ++r) { acc[r][0] = acc[r][1] = acc[r][2] = acc[r][3] = 0.f; }

    for (int jj = 0; jj < 16; ++jj) {
        int t = jj * 64 + tg * 4;
        const float* vp = vb + (size_t)t * DK + dg * 4;
        float4 v0 = *(const float4*)(vp);
        float4 v1 = *(const float4*)(vp + DK);
        float4 v2 = *(const float4*)(vp + 2 * DK);
        float4 v3 = *(const float4*)(vp + 3 * DK);
#pragma unroll
        for (int r = 0; r < RB; ++r) {
            float2 raw = *(const float2*)&e16[r][t];
            __half2* hp = (__half2*)&raw;
            float2 lo = __half22float2(hp[0]), hi = __half22float2(hp[1]);
            acc[r][0] = fmaf(lo.x, v0.x, fmaf(lo.y, v1.x, fmaf(hi.x, v2.x, fmaf(hi.y, v3.x, acc[r][0]))));
            acc[r][1] = fmaf(lo.x, v0.y, fmaf(lo.y, v1.y, fmaf(hi.x, v2.y, fmaf(hi.y, v3.y, acc[r][1]))));
            acc[r][2] = fmaf(lo.x, v0.z, fmaf(lo.y, v1.z, fmaf(hi.x, v2.z, fmaf(hi.y, v3.z, acc[r][2]))));
            acc[r][3] = fmaf(lo.x, v0.w, fmaf(lo.y, v1.w, fmaf(hi.x, v2.w, fmaf(hi.y, v3.w, acc[r][3]))));
        }
    }

    // ---- out reduce: reuse e16 buffer as fp32 [16][4][64] scratch, two rounds ----
    float* red = (float*)&e16[0][0];
#pragma unroll
    for (int h = 0; h < 2; ++h) {
        __syncthreads();    // previous readers of e16/red done
#pragma unroll
        for (int r = 0; r < 4; ++r) {
            *(float4*)&red[((size_t)tg * 4 + r) * 64 + dg * 4] =
                make_float4(acc[h * 4 + r][0], acc[h * 4 + r][1],
                            acc[h * 4 + r][2], acc[h * 4 + r][3]);
        }
        __syncthreads();
        int r2 = tid >> 6, d = tid & 63;
        float o = 0.f;
#pragma unroll
        for (int g = 0; g < 16; ++g) o += red[((size_t)g * 4 + r2) * 64 + d];
        out[((size_t)(gr0 + h * 4 + r2)) * DK + d] = o * inv_lds[h * 4 + r2];
    }
}

extern "C" void kernel_launch(void* const* d_in, const int* in_sizes, int n_in,
                              void* d_out, int out_size, void* d_ws, size_t ws_size,
                              hipStream_t stream) {
    const float* x       = (const float*)d_in[0];
    const float* theta_q = (const float*)d_in[1];
    const float* theta_k = (const float*)d_in[2];
    const float* W_v     = (const float*)d_in[3];
    const float* b_v     = (const float*)d_in[4];

    float* out  = (float*)d_out;                        // [8,1024,64]
    float* attn = (float*)d_out + (size_t)NB * NS * DK; // [8,1024,1024]

    float*  qd     = (float*)d_ws;                          // 1 MB fp32
    __half* kdh    = (__half*)(qd + (size_t)NB * NS * 32);  // 512 KB fp16
    float*  values = (float*)(kdh + (size_t)NB * NS * 32);  // 2 MB fp32

    prep_kernel<<<2048 + NB * NS * NQ / 256, 256, 0, stream>>>(
        x, theta_q, theta_k, W_v, b_v, qd, kdh, values);
    attn_kernel<<<NB * NS / RB, 256, 0, stream>>>(qd, kdh, values, out, attn);
}